// Round 8
// baseline (170.296 us; speedup 1.0000x reference)
//
#include <hip/hip_runtime.h>
#include <math.h>

#define NB 8
#define HH 256
#define WW 256
#define HW (HH*WW)

// ---- workspace layout (BYTE offsets) ----
#define OFF_AFFB  0UL                 // [8][8][256][256] bf16 planes (8388608 B)
#define OFF_W1FB  8388608UL           // [6][2][64][8] bf16 frag order (12288 B)
#define OFF_B1FB  8400896UL           // [32] fp32
#define OFF_W2FB  8401024UL           // [9][4][64][8] bf16 B-frag order (36864 B)
#define OFF_B2FB  8437888UL           // [64] fp32
#define OFF_W3FB  8438144UL           // [2][64][8] bf16 B-frag order (2048 B)
#define OFF_FEATS 8440192UL           // [8][256][256][16] bf16 (16777216 B)

typedef short  short8 __attribute__((ext_vector_type(8)));
typedef ushort u16x8  __attribute__((ext_vector_type(8)));
typedef ushort u16x4  __attribute__((ext_vector_type(4)));
typedef float  f32x4  __attribute__((ext_vector_type(4)));

__device__ __forceinline__ ushort f2bf(float x) {
  uint u = __float_as_uint(x);
  return (ushort)((u + 0x7FFFu + ((u >> 16) & 1u)) >> 16);
}
__device__ __forceinline__ float bf2f(ushort h) {
  uint u = ((uint)h) << 16;
  return __uint_as_float(u);
}
// packed f32x2 -> bf16x2 (RNE, identical to f2bf): low16 = a, high16 = b
__device__ __forceinline__ uint pk2bf(float a, float b) {
  uint r;
  asm("v_cvt_pk_bf16_f32 %0, %1, %2" : "=v"(r) : "v"(a), "v"(b));
  return r;
}

// ---------------- feats_row (blocks<2048): full feats, 1 row/block, gather via LDS ----------------
// blocks>=2048: weight prep
__global__ __launch_bounds__(256) void feats_row(
    const float* __restrict__ normal, const float* __restrict__ left,
    const float* __restrict__ right, const float* __restrict__ disp,
    const float* __restrict__ w1, const float* __restrict__ g1,
    const float* __restrict__ b1, const float* __restrict__ m1,
    const float* __restrict__ v1,
    const float* __restrict__ w2, const float* __restrict__ g2,
    const float* __restrict__ b2, const float* __restrict__ m2,
    const float* __restrict__ v2, const float* __restrict__ w3,
    char* __restrict__ wsb) {
  if (blockIdx.x >= 2048) {
    int idx = (blockIdx.x - 2048) * 256 + threadIdx.x;
    ushort* w1f = (ushort*)(wsb + OFF_W1FB);
    float* b1f  = (float*)(wsb + OFF_B1FB);
    ushort* w2f = (ushort*)(wsb + OFF_W2FB);
    float* b2f  = (float*)(wsb + OFF_B2FB);
    ushort* w3f = (ushort*)(wsb + OFF_W3FB);
    if (idx < 6144) {
      int jj = idx & 7;
      int lane = (idx >> 3) & 63;
      int nt = (idx >> 9) & 1;
      int s = idx >> 10;
      int ky = s >> 1, t = s & 1;
      int q = lane >> 4, lx = lane & 15;
      int k = q * 8 + jj;
      int dcol = k >> 4, ch = k & 15;
      int kx = t * 2 + dcol;
      int out = nt * 16 + lx;
      float inv = g1[out] / sqrtf(v1[out] + 1e-5f);
      float val = (ch < 12 && kx < 3) ? w1[((out * 12 + ch) * 3 + ky) * 3 + kx] * inv : 0.f;
      w1f[idx] = f2bf(val);
    }
    int j = idx - 6144;
    if (j >= 0 && j < 18432) {
      int kk   = j >> 11;
      int nt   = (j >> 9) & 3;
      int lane = (j >> 3) & 63;
      int jj   = j & 7;
      int q  = lane >> 4, lx = lane & 15;
      int cs = q * 8 + jj;                       // x1 LDS slot index
      int cin = ((cs & 1) << 4) | (cs >> 1);     // permuted conv1-output channel
      int out = nt * 16 + lx;
      float inv = g2[out] / sqrtf(v2[out] + 1e-5f);
      w2f[j] = f2bf(w2[(out * 32 + cin) * 9 + kk] * inv);
      if (kk == 0 && q == 0 && jj == 0) b2f[out] = b2[out] - m2[out] * inv;
    }
    int k2 = idx - 24576;
    if (k2 >= 0 && k2 < 32) {
      float inv = g1[k2] / sqrtf(v1[k2] + 1e-5f);
      b1f[k2] = b1[k2] - m1[k2] * inv;
    }
    int k3 = idx - 24608;
    if (k3 >= 0 && k3 < 1024) {
      int jj = k3 & 7;
      int lane = (k3 >> 3) & 63;
      int slice = k3 >> 9;
      int q = lane >> 4, lx = lane & 15;
      int cs = slice * 32 + q * 8 + jj;          // x2 LDS slot index
      int chp = ((cs & 3) << 4) | (cs >> 2);     // permuted conv2-output channel
      w3f[k3] = (lx < 8) ? f2bf(w3[lx * 64 + chp]) : (ushort)0;
    }
    return;
  }
  // one block = one output row (n, i); one thread = one pixel j
  __shared__ float curR[3][256];
  int blk = blockIdx.x;
  int n = blk >> 8;
  int i = blk & 255;
  int j = threadIdx.x;
  int i2 = i << 1;
  ushort* feats = (ushort*)(wsb + OFF_FEATS);
  float cl[3], cr[3];
#pragma unroll
  for (int c = 0; c < 3; ++c) {
    const float* Lp = left + ((size_t)(n * 3 + c) * 512 + i2) * 512 + (j << 1);
    float2 a0 = *(const float2*)Lp;
    float2 a1 = *(const float2*)(Lp + 512);
    cl[c] = 0.25f * (a0.x + a0.y + a1.x + a1.y);
    const float* Rp = right + ((size_t)(n * 3 + c) * 512 + i2) * 512 + (j << 1);
    float2 b0 = *(const float2*)Rp;
    float2 b1v = *(const float2*)(Rp + 512);
    cr[c] = 0.25f * (b0.x + b0.y + b1v.x + b1v.y);
    curR[c][j] = cr[c];
  }
  float nm[3];
#pragma unroll
  for (int c = 0; c < 3; ++c)
    nm[c] = normal[(size_t)(n * 3 + c) * HW + i * WW + j];
  float d = disp[(size_t)n * HW + i * WW + j];
  __syncthreads();
  float xs = (float)j - d;
  float x0f = floorf(xs);
  float fr = xs - x0f;
  int ix0 = (int)x0f;
  int ix1 = ix0 + 1;
  float vm0 = (ix0 >= 0 && ix0 < WW) ? 1.f : 0.f;
  float vm1 = (ix1 >= 0 && ix1 < WW) ? 1.f : 0.f;
  int x0c = min(max(ix0, 0), WW - 1);
  int x1c = min(max(ix1, 0), WW - 1);
  float tv[16];
#pragma unroll
  for (int c = 0; c < 3; ++c) {
    float warped = curR[c][x0c] * vm0 * (1.f - fr) + curR[c][x1c] * vm1 * fr;
    tv[9 + c] = fabsf(cl[c] - warped);
    tv[c] = nm[c];
    tv[3 + c] = cl[c];
    tv[6 + c] = cr[c];
  }
  uint pk[8];
#pragma unroll
  for (int k = 0; k < 6; ++k) pk[k] = pk2bf(tv[2 * k], tv[2 * k + 1]);
  pk[6] = 0u;
  pk[7] = 0u;
  size_t ob = ((size_t)((n << 16) + i * WW + j)) * 16;
  *(uint4*)&feats[ob] = make_uint4(pk[0], pk[1], pk[2], pk[3]);
  *(uint4*)&feats[ob + 8] = make_uint4(pk[4], pk[5], pk[6], pk[7]);
}

// ---------------- trunk: stage feats tile + conv1 + fused conv2/conv3 (2 barriers) ----------------
// 256 threads. LDS: buf[0..6464) = 808 16B chunks: feats tile [20][20][16ch], XOR-swizzled;
//   after conv1 this region is dead and becomes per-wave conv3 scratch (wid*1616, 16px x 70 ushorts).
// buf[6464..18128) = x1 tile [18 rows][18 cols][36 slots]
// x1 slot 2*lx+nt   <-> conv1 channel nt*16+lx (w2f permuted to match)
// x2 slot lx*4+nt   <-> conv2 channel nt*16+lx (w3f permuted to match)
// conv2+relayout+conv3+aff-store fused per-wave -> block barriers cut 4 -> 2.
__global__ __launch_bounds__(256) void trunk_kernel(char* __restrict__ wsb) {
  __shared__ __align__(16) ushort buf[18304];  // 36608 B
  ushort* x1t = buf + 6464;
  uint*   x1u = (uint*)x1t;
  const short8* __restrict__ w1fv = (const short8*)(wsb + OFF_W1FB);
  const float* __restrict__ b1f = (const float*)(wsb + OFF_B1FB);
  const short8* __restrict__ w2fv = (const short8*)(wsb + OFF_W2FB);
  const float* __restrict__ b2f = (const float*)(wsb + OFF_B2FB);
  const short8* __restrict__ w3fv = (const short8*)(wsb + OFF_W3FB);
  const ushort* __restrict__ feats = (const ushort*)(wsb + OFF_FEATS);
  ushort* aff = (ushort*)(wsb + OFF_AFFB);

  int blk = blockIdx.x;
  int n = blk >> 8;
  int t = blk & 255;
  int ty0 = (t >> 4) << 4;
  int tx0 = (t & 15) << 4;
  int tid = threadIdx.x;
  int lane = tid & 63;
  int wid = tid >> 6;
  int q = lane >> 4;
  int lx = lane & 15;
  bool border = (ty0 == 0) || (ty0 == 240) || (tx0 == 0) || (tx0 == 240);

  // ---- phase 1: stage feats 20x20x16 bf16 tile (XOR-swizzled 16B chunks) ----
  if (tid < 8) *(u16x8*)&buf[(800 + tid) * 8] = (u16x8)0;
  if (!border) {
    for (int e = tid; e < 800; e += 256) {
      int row = e / 40;
      int rem = e - row * 40;
      int gy = ty0 + row - 2, gx = tx0 + (rem >> 1) - 2;
      u16x8 v = *(const u16x8*)&feats[((size_t)((n << 16) + gy * WW + gx)) * 16 + (rem & 1) * 8];
      int slot = e ^ ((e >> 3) & 7);
      *(u16x8*)&buf[slot * 8] = v;
    }
  } else {
    for (int e = tid; e < 800; e += 256) {
      int row = e / 40;
      int rem = e - row * 40;
      int col = rem >> 1;
      int cc = rem & 1;
      int gy = ty0 + row - 2, gx = tx0 + col - 2;
      u16x8 v = (u16x8)0;
      if (gy >= 0 && gy < HH && gx >= 0 && gx < WW)
        v = *(const u16x8*)&feats[((size_t)((n << 16) + gy * WW + gx)) * 16 + cc * 8];
      int slot = e ^ ((e >> 3) & 7);
      *(u16x8*)&buf[slot * 8] = v;
    }
  }
  __syncthreads();

  // ---- phase 2: conv1, m-tile PAIRS for 4 independent MFMA chains per wave ----
  {
    short8 bw1[6][2];
#pragma unroll
    for (int s = 0; s < 6; ++s)
#pragma unroll
      for (int nt = 0; nt < 2; ++nt) bw1[s][nt] = w1fv[(s * 2 + nt) * 64 + lane];
    float bias1[2] = {b1f[lx], b1f[16 + lx]};
    int laneoff = (lx << 1) + ((q >> 1) << 1) + (q & 1);                 // main-tile lane offset
    int colbT = 32 + ((lx & 1) << 1) + ((q >> 1) << 1) + (q & 1);        // tail-tile col part
    int rowT = lx >> 1;                                                  // tail-tile row part
#pragma unroll
    for (int kpair = 0; kpair < 3; ++kpair) {
      int mA = wid + 8 * kpair;          // <= 19, always valid
      int mB = mA + 4;                   // may be >= 21
      bool vB = (mB < 21);
      f32x4 aA[2], aB[2];
      aA[0] = (f32x4)0.f; aA[1] = (f32x4)0.f;
      aB[0] = (f32x4)0.f; aB[1] = (f32x4)0.f;
      int GbA, GbB;
      if (mA < 18) GbA = mA * 40 + laneoff;
      else         GbA = min((mA - 18) * 8 + rowT, 17) * 40 + colbT;
      {
        int mBc = vB ? mB : mA;          // clamp: results discarded when !vB
        if (mBc < 18) GbB = mBc * 40 + laneoff;
        else          GbB = min((mBc - 18) * 8 + rowT, 17) * 40 + colbT;
      }
#pragma unroll
      for (int s = 0; s < 6; ++s) {
        int dG = (s >> 1) * 40 + (s & 1) * 4;
        int GA = GbA + dG;
        int GB = GbB + dG;
        int slA = GA ^ ((GA >> 3) & 7);
        int slB = GB ^ ((GB >> 3) & 7);
        short8 a0 = *(const short8*)&buf[slA * 8];
        short8 a1v = *(const short8*)&buf[slB * 8];
        aA[0] = __builtin_amdgcn_mfma_f32_16x16x32_bf16(a0, bw1[s][0], aA[0], 0, 0, 0);
        aA[1] = __builtin_amdgcn_mfma_f32_16x16x32_bf16(a0, bw1[s][1], aA[1], 0, 0, 0);
        aB[0] = __builtin_amdgcn_mfma_f32_16x16x32_bf16(a1v, bw1[s][0], aB[0], 0, 0, 0);
        aB[1] = __builtin_amdgcn_mfma_f32_16x16x32_bf16(a1v, bw1[s][1], aB[1], 0, 0, 0);
      }
      // epilogue for both tiles
#pragma unroll
      for (int u = 0; u < 2; ++u) {
        int m = u ? mB : mA;
        if (u && !vB) continue;
        f32x4* a1p = u ? aB : aA;
        if (m < 18) {
          int base = (m * 18 + (q << 2)) * 18 + lx;
          if (!border) {
#pragma unroll
            for (int r = 0; r < 4; ++r) {
              float v0 = fmaxf(a1p[0][r] + bias1[0], 0.f);
              float v1 = fmaxf(a1p[1][r] + bias1[1], 0.f);
              x1u[base + r * 18] = pk2bf(v0, v1);
            }
          } else {
            bool gyok = (unsigned)(ty0 + m - 1) < 256u;
            int gx0 = tx0 - 1 + (q << 2);
#pragma unroll
            for (int r = 0; r < 4; ++r) {
              bool ok = gyok && ((unsigned)(gx0 + r) < 256u);
              float v0 = ok ? fmaxf(a1p[0][r] + bias1[0], 0.f) : 0.f;
              float v1 = ok ? fmaxf(a1p[1][r] + bias1[1], 0.f) : 0.f;
              x1u[base + r * 18] = pk2bf(v0, v1);
            }
          }
        } else {
          int tb = m - 18;
#pragma unroll
          for (int r = 0; r < 4; ++r) {
            int io = (q << 2) + r;
            int hy = tb * 8 + (io >> 1);
            int hx = 16 + (io & 1);
            if (hy < 18) {
              float v0 = fmaxf(a1p[0][r] + bias1[0], 0.f);
              float v1 = fmaxf(a1p[1][r] + bias1[1], 0.f);
              if (border) {
                bool ok = ((unsigned)(ty0 + hy - 1) < 256u) && ((unsigned)(tx0 + hx - 1) < 256u);
                v0 = ok ? v0 : 0.f;
                v1 = ok ? v1 : 0.f;
              }
              x1u[(hy * 18 + hx) * 18 + lx] = pk2bf(v0, v1);
            }
          }
        }
      }
    }
  }
  __syncthreads();

  // ---- phase 3: conv2 + relayout + conv3 + aff store, fully per-wave (no block barriers) ----
  {
    f32x4 acc[4][4];
#pragma unroll
    for (int mt = 0; mt < 4; ++mt)
#pragma unroll
      for (int nt = 0; nt < 4; ++nt) acc[mt][nt] = (f32x4)0.f;
#pragma unroll
    for (int kk = 0; kk < 9; ++kk) {
      int ky = kk / 3, kx = kk - ky * 3;
      short8 a[4], b[4];
#pragma unroll
      for (int mt = 0; mt < 4; ++mt) {
        int row = wid * 4 + mt;
        a[mt] = *(const short8*)&x1t[((row + ky) * 18 + lx + kx) * 36 + q * 8];
      }
#pragma unroll
      for (int nt = 0; nt < 4; ++nt) b[nt] = w2fv[(kk * 4 + nt) * 64 + lane];
#pragma unroll
      for (int mt = 0; mt < 4; ++mt)
#pragma unroll
        for (int nt = 0; nt < 4; ++nt)
          acc[mt][nt] = __builtin_amdgcn_mfma_f32_16x16x32_bf16(a[mt], b[nt], acc[mt][nt], 0, 0, 0);
    }
    float bias2q[4] = {b2f[lx], b2f[16 + lx], b2f[32 + lx], b2f[48 + lx]};
    short8 bw3[2];
    bw3[0] = w3fv[lane];
    bw3[1] = w3fv[64 + lane];
    // per-wave scratch in the dead feats region: 16 px x 70 ushorts (2240 B), wave stride 3232 B
    ushort* scr = buf + wid * 1616;
#pragma unroll
    for (int mt = 0; mt < 4; ++mt) {
      // relayout this wave's row (wid*4+mt), 16 px, into [col][70] scratch
#pragma unroll
      for (int r = 0; r < 4; ++r) {
        int p = (q << 2) + r;    // px column
        uint2 pv;
        pv.x = pk2bf(fmaxf(acc[mt][0][r] + bias2q[0], 0.f),
                     fmaxf(acc[mt][1][r] + bias2q[1], 0.f));
        pv.y = pk2bf(fmaxf(acc[mt][2][r] + bias2q[2], 0.f),
                     fmaxf(acc[mt][3][r] + bias2q[3], 0.f));
        *(uint2*)&scr[p * 70 + (lx << 2)] = pv;
      }
      // intra-wave cross-lane RAW through LDS: force write completion, pin ordering
      asm volatile("s_waitcnt lgkmcnt(0)" ::: "memory");
      __builtin_amdgcn_sched_barrier(0);
      f32x4 a3acc = (f32x4)0.f;
#pragma unroll
      for (int s = 0; s < 2; ++s) {
        short8 a3 = *(const short8*)&scr[lx * 70 + s * 32 + q * 8];
        a3acc = __builtin_amdgcn_mfma_f32_16x16x32_bf16(a3, bw3[s], a3acc, 0, 0, 0);
      }
      // compiler fence: next mt's scratch writes must not hoist above these reads
      // (cross-lane WAR; HW LDS is in-order per wave, this pins the compiler)
      asm volatile("" ::: "memory");
      if (lx < 8) {
        int py = ty0 + wid * 4 + mt;
        int px = tx0 + (q << 2);
        uint2 pv;
        pv.x = pk2bf(fmaxf(a3acc[0], 0.f), fmaxf(a3acc[1], 0.f));
        pv.y = pk2bf(fmaxf(a3acc[2], 0.f), fmaxf(a3acc[3], 0.f));
        *(uint2*)&aff[((size_t)(n * 8 + lx)) * HW + (size_t)py * WW + px] = pv;
      }
    }
  }
}

// ---------------- final: 8-neighbor softmax propagation, 4 px/thread ----------------
__global__ __launch_bounds__(256) void final_kernel(const float* __restrict__ disp,
                                                    const char* __restrict__ wsb,
                                                    float* __restrict__ out) {
  int gid = blockIdx.x * 256 + threadIdx.x;
  int n = gid >> 14;
  int r = gid & 16383;
  int i = r >> 6;
  int j0 = (r & 63) << 2;
  const ushort* aff = (const ushort*)(wsb + OFF_AFFB);
  float d6[3][6];
#pragma unroll
  for (int rr = 0; rr < 3; ++rr) {
    int y = min(max(i + rr - 1, 0), HH - 1);
    const float* dp = disp + (size_t)n * HW + y * WW;
    float4 c4 = *(const float4*)(dp + j0);
    d6[rr][1] = c4.x; d6[rr][2] = c4.y; d6[rr][3] = c4.z; d6[rr][4] = c4.w;
    d6[rr][0] = dp[max(j0 - 1, 0)];
    d6[rr][5] = dp[min(j0 + 4, WW - 1)];
  }
  const int dy[8] = {1, 1, 1, 0, 0, -1, -1, -1};
  const int dx[8] = {1, 0, -1, 1, -1, 1, 0, -1};
  float g[8][4], dvv[8][4];
#pragma unroll
  for (int k = 0; k < 8; ++k) {
    int y = i + dy[k];
    bool vy = (y >= 0 && y < HH);
    int yc = min(max(y, 0), HH - 1);
    const ushort* ap = aff + ((size_t)(n * 8 + k)) * HW + (size_t)yc * WW;
    float w6[6];
    u16x4 c4 = *(const u16x4*)(ap + j0);
    w6[1] = bf2f(c4[0]); w6[2] = bf2f(c4[1]); w6[3] = bf2f(c4[2]); w6[4] = bf2f(c4[3]);
    w6[0] = bf2f(ap[max(j0 - 1, 0)]);
    w6[5] = bf2f(ap[min(j0 + 4, WW - 1)]);
    int rr = dy[k] + 1;
#pragma unroll
    for (int p = 0; p < 4; ++p) {
      int xp = j0 + p + dx[k];
      bool ok = vy && (xp >= 0) && (xp < WW);
      g[k][p] = ok ? w6[p + 1 + dx[k]] : 0.f;
      dvv[k][p] = ok ? d6[rr][p + 1 + dx[k]] : 0.f;
    }
  }
  float4 res;
#pragma unroll
  for (int p = 0; p < 4; ++p) {
    float m = g[0][p];
#pragma unroll
    for (int k = 1; k < 8; ++k) m = fmaxf(m, g[k][p]);
    float se = 0.f, sed = 0.f;
#pragma unroll
    for (int k = 0; k < 8; ++k) {
      float e = __expf(g[k][p] - m);
      se += e;
      sed += e * dvv[k][p];
    }
    float dc = d6[1][p + 1];
    (&res.x)[p] = 0.3f * (sed / se) + 0.7f * dc;
  }
  *(float4*)(out + (size_t)n * HW + i * WW + j0) = res;
}

extern "C" void kernel_launch(void* const* d_in, const int* in_sizes, int n_in,
                              void* d_out, int out_size, void* d_ws, size_t ws_size,
                              hipStream_t stream) {
  const float* normal = (const float*)d_in[0];
  const float* left   = (const float*)d_in[1];
  const float* right  = (const float*)d_in[2];
  const float* disp   = (const float*)d_in[3];
  const float* w1 = (const float*)d_in[4];
  const float* g1 = (const float*)d_in[5];
  const float* b1 = (const float*)d_in[6];
  const float* m1 = (const float*)d_in[7];
  const float* v1 = (const float*)d_in[8];
  const float* w2 = (const float*)d_in[9];
  const float* g2 = (const float*)d_in[10];
  const float* b2 = (const float*)d_in[11];
  const float* m2 = (const float*)d_in[12];
  const float* v2 = (const float*)d_in[13];
  const float* w3 = (const float*)d_in[14];
  char* wsb  = (char*)d_ws;
  float* out = (float*)d_out;

  hipLaunchKernelGGL(feats_row, dim3(2149), dim3(256), 0, stream,
                     normal, left, right, disp,
                     w1, g1, b1, m1, v1, w2, g2, b2, m2, v2, w3, wsb);
  hipLaunchKernelGGL(trunk_kernel, dim3(2048), dim3(256), 0, stream, wsb);
  hipLaunchKernelGGL(final_kernel, dim3(512), dim3(256), 0, stream, disp, wsb, out);
}

// Round 9
// 163.164 us; speedup vs baseline: 1.0437x; 1.0437x over previous
//
#include <hip/hip_runtime.h>
#include <math.h>

#define NB 8
#define HH 256
#define WW 256
#define HW (HH*WW)

// ---- workspace layout (BYTE offsets) ----
#define OFF_AFFB  0UL                 // [8][8][256][256] bf16 planes (8388608 B)
#define OFF_W1FB  8388608UL           // [6][2][64][8] bf16 frag order (12288 B)
#define OFF_B1FB  8400896UL           // [32] fp32
#define OFF_W2FB  8401024UL           // [9][4][64][8] bf16 B-frag order (36864 B)
#define OFF_B2FB  8437888UL           // [64] fp32
#define OFF_W3FB  8438144UL           // [2][64][8] bf16 B-frag order (2048 B)
#define OFF_FEATS 8440192UL           // [8][256][256][16] bf16 (16777216 B)

typedef short  short8 __attribute__((ext_vector_type(8)));
typedef ushort u16x8  __attribute__((ext_vector_type(8)));
typedef ushort u16x4  __attribute__((ext_vector_type(4)));
typedef float  f32x4  __attribute__((ext_vector_type(4)));

__device__ __forceinline__ ushort f2bf(float x) {
  uint u = __float_as_uint(x);
  return (ushort)((u + 0x7FFFu + ((u >> 16) & 1u)) >> 16);
}
__device__ __forceinline__ float bf2f(ushort h) {
  uint u = ((uint)h) << 16;
  return __uint_as_float(u);
}
// packed f32x2 -> bf16x2 (RNE, identical to f2bf): low16 = a, high16 = b
__device__ __forceinline__ uint pk2bf(float a, float b) {
  uint r;
  asm("v_cvt_pk_bf16_f32 %0, %1, %2" : "=v"(r) : "v"(a), "v"(b));
  return r;
}

// ---------------- feats_row (blocks<2048): full feats, 1 row/block, gather via LDS ----------------
// blocks>=2048: weight prep
__global__ __launch_bounds__(256) void feats_row(
    const float* __restrict__ normal, const float* __restrict__ left,
    const float* __restrict__ right, const float* __restrict__ disp,
    const float* __restrict__ w1, const float* __restrict__ g1,
    const float* __restrict__ b1, const float* __restrict__ m1,
    const float* __restrict__ v1,
    const float* __restrict__ w2, const float* __restrict__ g2,
    const float* __restrict__ b2, const float* __restrict__ m2,
    const float* __restrict__ v2, const float* __restrict__ w3,
    char* __restrict__ wsb) {
  if (blockIdx.x >= 2048) {
    int idx = (blockIdx.x - 2048) * 256 + threadIdx.x;
    ushort* w1f = (ushort*)(wsb + OFF_W1FB);
    float* b1f  = (float*)(wsb + OFF_B1FB);
    ushort* w2f = (ushort*)(wsb + OFF_W2FB);
    float* b2f  = (float*)(wsb + OFF_B2FB);
    ushort* w3f = (ushort*)(wsb + OFF_W3FB);
    if (idx < 6144) {
      int jj = idx & 7;
      int lane = (idx >> 3) & 63;
      int nt = (idx >> 9) & 1;
      int s = idx >> 10;
      int ky = s >> 1, t = s & 1;
      int q = lane >> 4, lx = lane & 15;
      int k = q * 8 + jj;
      int dcol = k >> 4, ch = k & 15;
      int kx = t * 2 + dcol;
      int out = nt * 16 + lx;
      float inv = g1[out] / sqrtf(v1[out] + 1e-5f);
      float val = (ch < 12 && kx < 3) ? w1[((out * 12 + ch) * 3 + ky) * 3 + kx] * inv : 0.f;
      w1f[idx] = f2bf(val);
    }
    int j = idx - 6144;
    if (j >= 0 && j < 18432) {
      int kk   = j >> 11;
      int nt   = (j >> 9) & 3;
      int lane = (j >> 3) & 63;
      int jj   = j & 7;
      int q  = lane >> 4, lx = lane & 15;
      int cs = q * 8 + jj;                       // x1 LDS slot index
      int cin = ((cs & 1) << 4) | (cs >> 1);     // permuted conv1-output channel
      int out = nt * 16 + lx;
      float inv = g2[out] / sqrtf(v2[out] + 1e-5f);
      w2f[j] = f2bf(w2[(out * 32 + cin) * 9 + kk] * inv);
      if (kk == 0 && q == 0 && jj == 0) b2f[out] = b2[out] - m2[out] * inv;
    }
    int k2 = idx - 24576;
    if (k2 >= 0 && k2 < 32) {
      float inv = g1[k2] / sqrtf(v1[k2] + 1e-5f);
      b1f[k2] = b1[k2] - m1[k2] * inv;
    }
    int k3 = idx - 24608;
    if (k3 >= 0 && k3 < 1024) {
      int jj = k3 & 7;
      int lane = (k3 >> 3) & 63;
      int slice = k3 >> 9;
      int q = lane >> 4, lx = lane & 15;
      int cs = slice * 32 + q * 8 + jj;          // x2 LDS slot index
      int chp = ((cs & 3) << 4) | (cs >> 2);     // permuted conv2-output channel
      w3f[k3] = (lx < 8) ? f2bf(w3[lx * 64 + chp]) : (ushort)0;
    }
    return;
  }
  // one block = one output row (n, i); one thread = one pixel j
  __shared__ float curR[3][256];
  int blk = blockIdx.x;
  int n = blk >> 8;
  int i = blk & 255;
  int j = threadIdx.x;
  int i2 = i << 1;
  ushort* feats = (ushort*)(wsb + OFF_FEATS);
  float cl[3], cr[3];
#pragma unroll
  for (int c = 0; c < 3; ++c) {
    const float* Lp = left + ((size_t)(n * 3 + c) * 512 + i2) * 512 + (j << 1);
    float2 a0 = *(const float2*)Lp;
    float2 a1 = *(const float2*)(Lp + 512);
    cl[c] = 0.25f * (a0.x + a0.y + a1.x + a1.y);
    const float* Rp = right + ((size_t)(n * 3 + c) * 512 + i2) * 512 + (j << 1);
    float2 b0 = *(const float2*)Rp;
    float2 b1v = *(const float2*)(Rp + 512);
    cr[c] = 0.25f * (b0.x + b0.y + b1v.x + b1v.y);
    curR[c][j] = cr[c];
  }
  float nm[3];
#pragma unroll
  for (int c = 0; c < 3; ++c)
    nm[c] = normal[(size_t)(n * 3 + c) * HW + i * WW + j];
  float d = disp[(size_t)n * HW + i * WW + j];
  __syncthreads();
  float xs = (float)j - d;
  float x0f = floorf(xs);
  float fr = xs - x0f;
  int ix0 = (int)x0f;
  int ix1 = ix0 + 1;
  float vm0 = (ix0 >= 0 && ix0 < WW) ? 1.f : 0.f;
  float vm1 = (ix1 >= 0 && ix1 < WW) ? 1.f : 0.f;
  int x0c = min(max(ix0, 0), WW - 1);
  int x1c = min(max(ix1, 0), WW - 1);
  float tv[16];
#pragma unroll
  for (int c = 0; c < 3; ++c) {
    float warped = curR[c][x0c] * vm0 * (1.f - fr) + curR[c][x1c] * vm1 * fr;
    tv[9 + c] = fabsf(cl[c] - warped);
    tv[c] = nm[c];
    tv[3 + c] = cl[c];
    tv[6 + c] = cr[c];
  }
  uint pk[8];
#pragma unroll
  for (int k = 0; k < 6; ++k) pk[k] = pk2bf(tv[2 * k], tv[2 * k + 1]);
  pk[6] = 0u;
  pk[7] = 0u;
  size_t ob = ((size_t)((n << 16) + i * WW + j)) * 16;
  *(uint4*)&feats[ob] = make_uint4(pk[0], pk[1], pk[2], pk[3]);
  *(uint4*)&feats[ob + 8] = make_uint4(pk[4], pk[5], pk[6], pk[7]);
}

// ---------------- trunk: stage feats tile + conv1 + conv2 + conv3 (R6 structure) ----------------
// XCD swizzle: 2048 blocks = 8 XCDs x 256; (bid&7)*256 + bid>>3 puts one full image
// (2.1 MB feats, fits 4 MB XCD L2) on each XCD -> halo re-reads become L2 hits.
// 256 threads. LDS: buf[0..6464) = 808 16B chunks: feats tile [20][20][16ch], XOR-swizzled
//      buf[6464..18128) = x1 tile [18*18][36 slots]; phase-4 relayout overlays [0..17408) stride 68
// x1 slot 2*lx+nt   <-> conv1 channel nt*16+lx (w2f permuted to match)
// x2 slot lx*4+nt   <-> conv2 channel nt*16+lx (w3f permuted to match)
__global__ __launch_bounds__(256) void trunk_kernel(char* __restrict__ wsb) {
  __shared__ __align__(16) ushort buf[18304];  // 36608 B
  ushort* x1t = buf + 6464;
  uint*   x1u = (uint*)x1t;
  const short8* __restrict__ w1fv = (const short8*)(wsb + OFF_W1FB);
  const float* __restrict__ b1f = (const float*)(wsb + OFF_B1FB);
  const short8* __restrict__ w2fv = (const short8*)(wsb + OFF_W2FB);
  const float* __restrict__ b2f = (const float*)(wsb + OFF_B2FB);
  const short8* __restrict__ w3fv = (const short8*)(wsb + OFF_W3FB);
  const ushort* __restrict__ feats = (const ushort*)(wsb + OFF_FEATS);
  ushort* aff = (ushort*)(wsb + OFF_AFFB);

  int bid = blockIdx.x;
  int blk = ((bid & 7) << 8) + (bid >> 3);   // bijective XCD swizzle (2048 % 8 == 0)
  int n = blk >> 8;
  int t = blk & 255;
  int ty0 = (t >> 4) << 4;
  int tx0 = (t & 15) << 4;
  int tid = threadIdx.x;
  int lane = tid & 63;
  int wid = tid >> 6;
  int q = lane >> 4;
  int lx = lane & 15;
  bool border = (ty0 == 0) || (ty0 == 240) || (tx0 == 0) || (tx0 == 240);

  // ---- phase 1: stage feats 20x20x16 bf16 tile (XOR-swizzled 16B chunks) ----
  if (tid < 8) *(u16x8*)&buf[(800 + tid) * 8] = (u16x8)0;
  if (!border) {
    for (int e = tid; e < 800; e += 256) {
      int row = e / 40;
      int rem = e - row * 40;
      int gy = ty0 + row - 2, gx = tx0 + (rem >> 1) - 2;
      u16x8 v = *(const u16x8*)&feats[((size_t)((n << 16) + gy * WW + gx)) * 16 + (rem & 1) * 8];
      int slot = e ^ ((e >> 3) & 7);
      *(u16x8*)&buf[slot * 8] = v;
    }
  } else {
    for (int e = tid; e < 800; e += 256) {
      int row = e / 40;
      int rem = e - row * 40;
      int col = rem >> 1;
      int cc = rem & 1;
      int gy = ty0 + row - 2, gx = tx0 + col - 2;
      u16x8 v = (u16x8)0;
      if (gy >= 0 && gy < HH && gx >= 0 && gx < WW)
        v = *(const u16x8*)&feats[((size_t)((n << 16) + gy * WW + gx)) * 16 + cc * 8];
      int slot = e ^ ((e >> 3) & 7);
      *(u16x8*)&buf[slot * 8] = v;
    }
  }
  __syncthreads();

  // ---- phase 2: conv1, m-tile PAIRS for 4 independent MFMA chains per wave ----
  {
    short8 bw1[6][2];
#pragma unroll
    for (int s = 0; s < 6; ++s)
#pragma unroll
      for (int nt = 0; nt < 2; ++nt) bw1[s][nt] = w1fv[(s * 2 + nt) * 64 + lane];
    float bias1[2] = {b1f[lx], b1f[16 + lx]};
    int laneoff = (lx << 1) + ((q >> 1) << 1) + (q & 1);                 // main-tile lane offset
    int colbT = 32 + ((lx & 1) << 1) + ((q >> 1) << 1) + (q & 1);        // tail-tile col part
    int rowT = lx >> 1;                                                  // tail-tile row part
#pragma unroll
    for (int kpair = 0; kpair < 3; ++kpair) {
      int mA = wid + 8 * kpair;          // <= 19, always valid
      int mB = mA + 4;                   // may be >= 21
      bool vB = (mB < 21);
      f32x4 aA[2], aB[2];
      aA[0] = (f32x4)0.f; aA[1] = (f32x4)0.f;
      aB[0] = (f32x4)0.f; aB[1] = (f32x4)0.f;
      int GbA, GbB;
      if (mA < 18) GbA = mA * 40 + laneoff;
      else         GbA = min((mA - 18) * 8 + rowT, 17) * 40 + colbT;
      {
        int mBc = vB ? mB : mA;          // clamp: results discarded when !vB
        if (mBc < 18) GbB = mBc * 40 + laneoff;
        else          GbB = min((mBc - 18) * 8 + rowT, 17) * 40 + colbT;
      }
#pragma unroll
      for (int s = 0; s < 6; ++s) {
        int dG = (s >> 1) * 40 + (s & 1) * 4;
        int GA = GbA + dG;
        int GB = GbB + dG;
        int slA = GA ^ ((GA >> 3) & 7);
        int slB = GB ^ ((GB >> 3) & 7);
        short8 a0 = *(const short8*)&buf[slA * 8];
        short8 a1v = *(const short8*)&buf[slB * 8];
        aA[0] = __builtin_amdgcn_mfma_f32_16x16x32_bf16(a0, bw1[s][0], aA[0], 0, 0, 0);
        aA[1] = __builtin_amdgcn_mfma_f32_16x16x32_bf16(a0, bw1[s][1], aA[1], 0, 0, 0);
        aB[0] = __builtin_amdgcn_mfma_f32_16x16x32_bf16(a1v, bw1[s][0], aB[0], 0, 0, 0);
        aB[1] = __builtin_amdgcn_mfma_f32_16x16x32_bf16(a1v, bw1[s][1], aB[1], 0, 0, 0);
      }
      // epilogue for both tiles
#pragma unroll
      for (int u = 0; u < 2; ++u) {
        int m = u ? mB : mA;
        if (u && !vB) continue;
        f32x4* a1p = u ? aB : aA;
        if (m < 18) {
          int base = (m * 18 + (q << 2)) * 18 + lx;
          if (!border) {
#pragma unroll
            for (int r = 0; r < 4; ++r) {
              float v0 = fmaxf(a1p[0][r] + bias1[0], 0.f);
              float v1 = fmaxf(a1p[1][r] + bias1[1], 0.f);
              x1u[base + r * 18] = pk2bf(v0, v1);
            }
          } else {
            bool gyok = (unsigned)(ty0 + m - 1) < 256u;
            int gx0 = tx0 - 1 + (q << 2);
#pragma unroll
            for (int r = 0; r < 4; ++r) {
              bool ok = gyok && ((unsigned)(gx0 + r) < 256u);
              float v0 = ok ? fmaxf(a1p[0][r] + bias1[0], 0.f) : 0.f;
              float v1 = ok ? fmaxf(a1p[1][r] + bias1[1], 0.f) : 0.f;
              x1u[base + r * 18] = pk2bf(v0, v1);
            }
          }
        } else {
          int tb = m - 18;
#pragma unroll
          for (int r = 0; r < 4; ++r) {
            int io = (q << 2) + r;
            int hy = tb * 8 + (io >> 1);
            int hx = 16 + (io & 1);
            if (hy < 18) {
              float v0 = fmaxf(a1p[0][r] + bias1[0], 0.f);
              float v1 = fmaxf(a1p[1][r] + bias1[1], 0.f);
              if (border) {
                bool ok = ((unsigned)(ty0 + hy - 1) < 256u) && ((unsigned)(tx0 + hx - 1) < 256u);
                v0 = ok ? v0 : 0.f;
                v1 = ok ? v1 : 0.f;
              }
              x1u[(hy * 18 + hx) * 18 + lx] = pk2bf(v0, v1);
            }
          }
        }
      }
    }
  }
  __syncthreads();

  // ---- phase 3: conv2 MFMA, software-pipelined a/b loads (kk+1 prefetch) ----
  f32x4 acc[4][4];
#pragma unroll
  for (int mt = 0; mt < 4; ++mt)
#pragma unroll
    for (int nt = 0; nt < 4; ++nt) acc[mt][nt] = (f32x4)0.f;
  {
    short8 bcur[4], acur[4];
#pragma unroll
    for (int nt = 0; nt < 4; ++nt) bcur[nt] = w2fv[nt * 64 + lane];
#pragma unroll
    for (int mt = 0; mt < 4; ++mt) {
      int row = wid * 4 + mt;
      acur[mt] = *(const short8*)&x1t[(row * 18 + lx) * 36 + q * 8];  // ky=0,kx=0
    }
#pragma unroll
    for (int kk = 0; kk < 9; ++kk) {
      short8 bnxt[4], anxt[4];
      if (kk < 8) {
        int kn = kk + 1;
        int ky = kn / 3, kx = kn - ky * 3;
#pragma unroll
        for (int nt = 0; nt < 4; ++nt) bnxt[nt] = w2fv[(kn * 4 + nt) * 64 + lane];
#pragma unroll
        for (int mt = 0; mt < 4; ++mt) {
          int row = wid * 4 + mt;
          anxt[mt] = *(const short8*)&x1t[((row + ky) * 18 + lx + kx) * 36 + q * 8];
        }
      }
#pragma unroll
      for (int mt = 0; mt < 4; ++mt)
#pragma unroll
        for (int nt = 0; nt < 4; ++nt)
          acc[mt][nt] = __builtin_amdgcn_mfma_f32_16x16x32_bf16(acur[mt], bcur[nt], acc[mt][nt], 0, 0, 0);
      if (kk < 8) {
#pragma unroll
        for (int nt = 0; nt < 4; ++nt) bcur[nt] = bnxt[nt];
#pragma unroll
        for (int mt = 0; mt < 4; ++mt) acur[mt] = anxt[mt];
      }
    }
  }
  float bias2q[4] = {b2f[lx], b2f[16 + lx], b2f[32 + lx], b2f[48 + lx]};
  __syncthreads();

  // ---- phase 4: relayout D -> [pixel][slot] bf16, packed 8B stores ----
#pragma unroll
  for (int mt = 0; mt < 4; ++mt) {
    int row = wid * 4 + mt;
#pragma unroll
    for (int r = 0; r < 4; ++r) {
      int p = row * 16 + (q << 2) + r;
      float c0 = fmaxf(acc[mt][0][r] + bias2q[0], 0.f);
      float c1 = fmaxf(acc[mt][1][r] + bias2q[1], 0.f);
      float c2 = fmaxf(acc[mt][2][r] + bias2q[2], 0.f);
      float c3 = fmaxf(acc[mt][3][r] + bias2q[3], 0.f);
      uint2 pv;
      pv.x = pk2bf(c0, c1);
      pv.y = pk2bf(c2, c3);
      *(uint2*)&buf[p * 68 + (lx << 2)] = pv;
    }
  }
  __syncthreads();

  // ---- phase 5: conv3 1x1 64->8 via MFMA + store aff ----
  short8 bw3[2];
  bw3[0] = w3fv[lane];
  bw3[1] = w3fv[64 + lane];
  f32x4 acc3[4];
#pragma unroll
  for (int mt = 0; mt < 4; ++mt) acc3[mt] = (f32x4)0.f;
#pragma unroll
  for (int mt = 0; mt < 4; ++mt) {
    int p = wid * 64 + mt * 16 + lx;
#pragma unroll
    for (int s = 0; s < 2; ++s) {
      short8 a3 = *(const short8*)&buf[p * 68 + s * 32 + q * 8];
      acc3[mt] = __builtin_amdgcn_mfma_f32_16x16x32_bf16(a3, bw3[s], acc3[mt], 0, 0, 0);
    }
  }
  if (lx < 8) {
#pragma unroll
    for (int mt = 0; mt < 4; ++mt) {
      int py = ty0 + wid * 4 + mt;
      int px = tx0 + (q << 2);
      uint2 pv;
      pv.x = pk2bf(fmaxf(acc3[mt][0], 0.f), fmaxf(acc3[mt][1], 0.f));
      pv.y = pk2bf(fmaxf(acc3[mt][2], 0.f), fmaxf(acc3[mt][3], 0.f));
      *(uint2*)&aff[((size_t)(n * 8 + lx)) * HW + (size_t)py * WW + px] = pv;
    }
  }
}

// ---------------- final: 8-neighbor softmax propagation, 4 px/thread ----------------
// XCD swizzle: 512 blocks = 8 x 64; one image's aff (1.05 MB) per XCD.
__global__ __launch_bounds__(256) void final_kernel(const float* __restrict__ disp,
                                                    const char* __restrict__ wsb,
                                                    float* __restrict__ out) {
  int bid = blockIdx.x;
  int sblk = ((bid & 7) << 6) + (bid >> 3);   // bijective (512 % 8 == 0)
  int gid = sblk * 256 + threadIdx.x;
  int n = gid >> 14;
  int r = gid & 16383;
  int i = r >> 6;
  int j0 = (r & 63) << 2;
  const ushort* aff = (const ushort*)(wsb + OFF_AFFB);
  float d6[3][6];
#pragma unroll
  for (int rr = 0; rr < 3; ++rr) {
    int y = min(max(i + rr - 1, 0), HH - 1);
    const float* dp = disp + (size_t)n * HW + y * WW;
    float4 c4 = *(const float4*)(dp + j0);
    d6[rr][1] = c4.x; d6[rr][2] = c4.y; d6[rr][3] = c4.z; d6[rr][4] = c4.w;
    d6[rr][0] = dp[max(j0 - 1, 0)];
    d6[rr][5] = dp[min(j0 + 4, WW - 1)];
  }
  const int dy[8] = {1, 1, 1, 0, 0, -1, -1, -1};
  const int dx[8] = {1, 0, -1, 1, -1, 1, 0, -1};
  float g[8][4], dvv[8][4];
#pragma unroll
  for (int k = 0; k < 8; ++k) {
    int y = i + dy[k];
    bool vy = (y >= 0 && y < HH);
    int yc = min(max(y, 0), HH - 1);
    const ushort* ap = aff + ((size_t)(n * 8 + k)) * HW + (size_t)yc * WW;
    float w6[6];
    u16x4 c4 = *(const u16x4*)(ap + j0);
    w6[1] = bf2f(c4[0]); w6[2] = bf2f(c4[1]); w6[3] = bf2f(c4[2]); w6[4] = bf2f(c4[3]);
    w6[0] = bf2f(ap[max(j0 - 1, 0)]);
    w6[5] = bf2f(ap[min(j0 + 4, WW - 1)]);
    int rr = dy[k] + 1;
#pragma unroll
    for (int p = 0; p < 4; ++p) {
      int xp = j0 + p + dx[k];
      bool ok = vy && (xp >= 0) && (xp < WW);
      g[k][p] = ok ? w6[p + 1 + dx[k]] : 0.f;
      dvv[k][p] = ok ? d6[rr][p + 1 + dx[k]] : 0.f;
    }
  }
  float4 res;
#pragma unroll
  for (int p = 0; p < 4; ++p) {
    float m = g[0][p];
#pragma unroll
    for (int k = 1; k < 8; ++k) m = fmaxf(m, g[k][p]);
    float se = 0.f, sed = 0.f;
#pragma unroll
    for (int k = 0; k < 8; ++k) {
      float e = __expf(g[k][p] - m);
      se += e;
      sed += e * dvv[k][p];
    }
    float dc = d6[1][p + 1];
    (&res.x)[p] = 0.3f * (sed / se) + 0.7f * dc;
  }
  *(float4*)(out + (size_t)n * HW + i * WW + j0) = res;
}

extern "C" void kernel_launch(void* const* d_in, const int* in_sizes, int n_in,
                              void* d_out, int out_size, void* d_ws, size_t ws_size,
                              hipStream_t stream) {
  const float* normal = (const float*)d_in[0];
  const float* left   = (const float*)d_in[1];
  const float* right  = (const float*)d_in[2];
  const float* disp   = (const float*)d_in[3];
  const float* w1 = (const float*)d_in[4];
  const float* g1 = (const float*)d_in[5];
  const float* b1 = (const float*)d_in[6];
  const float* m1 = (const float*)d_in[7];
  const float* v1 = (const float*)d_in[8];
  const float* w2 = (const float*)d_in[9];
  const float* g2 = (const float*)d_in[10];
  const float* b2 = (const float*)d_in[11];
  const float* m2 = (const float*)d_in[12];
  const float* v2 = (const float*)d_in[13];
  const float* w3 = (const float*)d_in[14];
  char* wsb  = (char*)d_ws;
  float* out = (float*)d_out;

  hipLaunchKernelGGL(feats_row, dim3(2149), dim3(256), 0, stream,
                     normal, left, right, disp,
                     w1, g1, b1, m1, v1, w2, g2, b2, m2, v2, w3, wsb);
  hipLaunchKernelGGL(trunk_kernel, dim3(2048), dim3(256), 0, stream, wsb);
  hipLaunchKernelGGL(final_kernel, dim3(512), dim3(256), 0, stream, disp, wsb, out);
}

// Round 10
// 159.844 us; speedup vs baseline: 1.0654x; 1.0208x over previous
//
#include <hip/hip_runtime.h>
#include <math.h>

#define NB 8
#define HH 256
#define WW 256
#define HW (HH*WW)

// ---- workspace layout (BYTE offsets) ----
#define OFF_AFFB  0UL                 // [8][8][256][256] bf16 planes (8388608 B)
#define OFF_W1FB  8388608UL           // [6][2][64][8] bf16 frag order (12288 B)
#define OFF_B1FB  8400896UL           // [32] fp32
#define OFF_W2FB  8401024UL           // [9][4][64][8] bf16 B-frag order (36864 B)
#define OFF_B2FB  8437888UL           // [64] fp32
#define OFF_W3FB  8438144UL           // [2][64][8] bf16 B-frag order (2048 B)
#define OFF_FEATS 8440192UL           // [8][256][256][16] bf16 (16777216 B)

typedef short  short8 __attribute__((ext_vector_type(8)));
typedef ushort u16x8  __attribute__((ext_vector_type(8)));
typedef ushort u16x4  __attribute__((ext_vector_type(4)));
typedef float  f32x4  __attribute__((ext_vector_type(4)));

__device__ __forceinline__ ushort f2bf(float x) {
  uint u = __float_as_uint(x);
  return (ushort)((u + 0x7FFFu + ((u >> 16) & 1u)) >> 16);
}
__device__ __forceinline__ float bf2f(ushort h) {
  uint u = ((uint)h) << 16;
  return __uint_as_float(u);
}
// packed f32x2 -> bf16x2 (RNE, identical to f2bf): low16 = a, high16 = b
__device__ __forceinline__ uint pk2bf(float a, float b) {
  uint r;
  asm("v_cvt_pk_bf16_f32 %0, %1, %2" : "=v"(r) : "v"(a), "v"(b));
  return r;
}

// ---------------- feats_row (blocks<2048): full feats, 1 row/block, gather via LDS ----------------
// blocks>=2048: weight prep
__global__ __launch_bounds__(256) void feats_row(
    const float* __restrict__ normal, const float* __restrict__ left,
    const float* __restrict__ right, const float* __restrict__ disp,
    const float* __restrict__ w1, const float* __restrict__ g1,
    const float* __restrict__ b1, const float* __restrict__ m1,
    const float* __restrict__ v1,
    const float* __restrict__ w2, const float* __restrict__ g2,
    const float* __restrict__ b2, const float* __restrict__ m2,
    const float* __restrict__ v2, const float* __restrict__ w3,
    char* __restrict__ wsb) {
  if (blockIdx.x >= 2048) {
    int idx = (blockIdx.x - 2048) * 256 + threadIdx.x;
    ushort* w1f = (ushort*)(wsb + OFF_W1FB);
    float* b1f  = (float*)(wsb + OFF_B1FB);
    ushort* w2f = (ushort*)(wsb + OFF_W2FB);
    float* b2f  = (float*)(wsb + OFF_B2FB);
    ushort* w3f = (ushort*)(wsb + OFF_W3FB);
    if (idx < 6144) {
      int jj = idx & 7;
      int lane = (idx >> 3) & 63;
      int nt = (idx >> 9) & 1;
      int s = idx >> 10;
      int ky = s >> 1, t = s & 1;
      int q = lane >> 4, lx = lane & 15;
      int k = q * 8 + jj;
      int dcol = k >> 4, ch = k & 15;
      int kx = t * 2 + dcol;
      int out = nt * 16 + lx;
      float inv = g1[out] / sqrtf(v1[out] + 1e-5f);
      float val = (ch < 12 && kx < 3) ? w1[((out * 12 + ch) * 3 + ky) * 3 + kx] * inv : 0.f;
      w1f[idx] = f2bf(val);
    }
    int j = idx - 6144;
    if (j >= 0 && j < 18432) {
      int kk   = j >> 11;
      int nt   = (j >> 9) & 3;
      int lane = (j >> 3) & 63;
      int jj   = j & 7;
      int q  = lane >> 4, lx = lane & 15;
      int cs = q * 8 + jj;                       // x1 LDS slot index
      int cin = ((cs & 1) << 4) | (cs >> 1);     // permuted conv1-output channel
      int out = nt * 16 + lx;
      float inv = g2[out] / sqrtf(v2[out] + 1e-5f);
      w2f[j] = f2bf(w2[(out * 32 + cin) * 9 + kk] * inv);
      if (kk == 0 && q == 0 && jj == 0) b2f[out] = b2[out] - m2[out] * inv;
    }
    int k2 = idx - 24576;
    if (k2 >= 0 && k2 < 32) {
      float inv = g1[k2] / sqrtf(v1[k2] + 1e-5f);
      b1f[k2] = b1[k2] - m1[k2] * inv;
    }
    int k3 = idx - 24608;
    if (k3 >= 0 && k3 < 1024) {
      int jj = k3 & 7;
      int lane = (k3 >> 3) & 63;
      int slice = k3 >> 9;
      int q = lane >> 4, lx = lane & 15;
      int cs = slice * 32 + q * 8 + jj;          // x2 LDS slot index
      int chp = ((cs & 3) << 4) | (cs >> 2);     // permuted conv2-output channel
      w3f[k3] = (lx < 8) ? f2bf(w3[lx * 64 + chp]) : (ushort)0;
    }
    return;
  }
  // one block = one output row (n, i); one thread = one pixel j
  __shared__ float curR[3][256];
  int blk = blockIdx.x;
  int n = blk >> 8;
  int i = blk & 255;
  int j = threadIdx.x;
  int i2 = i << 1;
  ushort* feats = (ushort*)(wsb + OFF_FEATS);
  float cl[3], cr[3];
#pragma unroll
  for (int c = 0; c < 3; ++c) {
    const float* Lp = left + ((size_t)(n * 3 + c) * 512 + i2) * 512 + (j << 1);
    float2 a0 = *(const float2*)Lp;
    float2 a1 = *(const float2*)(Lp + 512);
    cl[c] = 0.25f * (a0.x + a0.y + a1.x + a1.y);
    const float* Rp = right + ((size_t)(n * 3 + c) * 512 + i2) * 512 + (j << 1);
    float2 b0 = *(const float2*)Rp;
    float2 b1v = *(const float2*)(Rp + 512);
    cr[c] = 0.25f * (b0.x + b0.y + b1v.x + b1v.y);
    curR[c][j] = cr[c];
  }
  float nm[3];
#pragma unroll
  for (int c = 0; c < 3; ++c)
    nm[c] = normal[(size_t)(n * 3 + c) * HW + i * WW + j];
  float d = disp[(size_t)n * HW + i * WW + j];
  __syncthreads();
  float xs = (float)j - d;
  float x0f = floorf(xs);
  float fr = xs - x0f;
  int ix0 = (int)x0f;
  int ix1 = ix0 + 1;
  float vm0 = (ix0 >= 0 && ix0 < WW) ? 1.f : 0.f;
  float vm1 = (ix1 >= 0 && ix1 < WW) ? 1.f : 0.f;
  int x0c = min(max(ix0, 0), WW - 1);
  int x1c = min(max(ix1, 0), WW - 1);
  float tv[16];
#pragma unroll
  for (int c = 0; c < 3; ++c) {
    float warped = curR[c][x0c] * vm0 * (1.f - fr) + curR[c][x1c] * vm1 * fr;
    tv[9 + c] = fabsf(cl[c] - warped);
    tv[c] = nm[c];
    tv[3 + c] = cl[c];
    tv[6 + c] = cr[c];
  }
  uint pk[8];
#pragma unroll
  for (int k = 0; k < 6; ++k) pk[k] = pk2bf(tv[2 * k], tv[2 * k + 1]);
  pk[6] = 0u;
  pk[7] = 0u;
  size_t ob = ((size_t)((n << 16) + i * WW + j)) * 16;
  *(uint4*)&feats[ob] = make_uint4(pk[0], pk[1], pk[2], pk[3]);
  *(uint4*)&feats[ob + 8] = make_uint4(pk[4], pk[5], pk[6], pk[7]);
}

// ---------------- trunk: 32x16 output tile per block (1024 blocks), 256 threads ----------------
// XCD swizzle: 1024 = 8 x 128 -> one image per XCD (feats slice 2.1 MB fits 4 MB XCD L2).
// LDS (ushort idx): feats [36 rows][20 cols][16ch] = 1440 swizzled 16B chunks + 8 guard = [0,11584)
//   x1 [34 rows][18 cols][36 slots] = [11584,33616)
//   relayout overlay (per half): [pixel p][68], p in [0,256), u <= 17403 -- clobbers feats (dead)
//   and x1 rows 0..8 (only read by conv2-h0, which a barrier protects). conv2-h1 reads x1 rows
//   >=16 (u >= 21952) -- never clobbered, so no further barriers needed.
// Per-wave overlay region p in [wid*64, wid*64+64) is written AND read only by that wave.
// x1 slot 2*lx+nt <-> conv1 ch nt*16+lx; x2 slot lx*4+nt <-> conv2 ch nt*16+lx (weights permuted).
__global__ __launch_bounds__(256) void trunk_kernel(char* __restrict__ wsb) {
  __shared__ __align__(16) ushort buf[33616];  // 67232 B -> 2 blocks/CU
  ushort* x1t = buf + 11584;
  uint*   x1u = (uint*)x1t;
  const short8* __restrict__ w1fv = (const short8*)(wsb + OFF_W1FB);
  const float* __restrict__ b1f = (const float*)(wsb + OFF_B1FB);
  const short8* __restrict__ w2fv = (const short8*)(wsb + OFF_W2FB);
  const float* __restrict__ b2f = (const float*)(wsb + OFF_B2FB);
  const short8* __restrict__ w3fv = (const short8*)(wsb + OFF_W3FB);
  const ushort* __restrict__ feats = (const ushort*)(wsb + OFF_FEATS);
  ushort* aff = (ushort*)(wsb + OFF_AFFB);

  int bid = blockIdx.x;
  int blk = ((bid & 7) << 7) + (bid >> 3);   // bijective XCD swizzle (1024 % 8 == 0)
  int n = blk >> 7;
  int t = blk & 127;
  int ty0 = (t >> 4) << 5;                   // 8 row-tiles of 32
  int tx0 = (t & 15) << 4;                   // 16 col-tiles of 16
  int tid = threadIdx.x;
  int lane = tid & 63;
  int wid = tid >> 6;
  int q = lane >> 4;
  int lx = lane & 15;
  bool border = (ty0 == 0) || (ty0 == 224) || (tx0 == 0) || (tx0 == 240);

  // ---- phase 1: stage feats 36x20x16 bf16 tile (XOR-swizzled 16B chunks) ----
  if (tid < 8) {
    int e = 1440 + tid;
    int s = e ^ ((e >> 3) & 7);
    *(u16x8*)&buf[s * 8] = (u16x8)0;   // guard chunks (kx=3 zero-weight reads)
  }
  if (!border) {
    for (int e = tid; e < 1440; e += 256) {
      int row = e / 40;
      int rem = e - row * 40;
      int gy = ty0 + row - 2, gx = tx0 + (rem >> 1) - 2;
      u16x8 v = *(const u16x8*)&feats[((size_t)((n << 16) + gy * WW + gx)) * 16 + (rem & 1) * 8];
      int slot = e ^ ((e >> 3) & 7);
      *(u16x8*)&buf[slot * 8] = v;
    }
  } else {
    for (int e = tid; e < 1440; e += 256) {
      int row = e / 40;
      int rem = e - row * 40;
      int col = rem >> 1;
      int cc = rem & 1;
      int gy = ty0 + row - 2, gx = tx0 + col - 2;
      u16x8 v = (u16x8)0;
      if (gy >= 0 && gy < HH && gx >= 0 && gx < WW)
        v = *(const u16x8*)&feats[((size_t)((n << 16) + gy * WW + gx)) * 16 + cc * 8];
      int slot = e ^ ((e >> 3) & 7);
      *(u16x8*)&buf[slot * 8] = v;
    }
  }
  __syncthreads();

  // ---- phase 2: conv1 over 34x18 x1 grid: 34 main row-tiles + 5 tail tiles (cols 16,17) ----
  {
    short8 bw1[6][2];
#pragma unroll
    for (int s = 0; s < 6; ++s)
#pragma unroll
      for (int nt = 0; nt < 2; ++nt) bw1[s][nt] = w1fv[(s * 2 + nt) * 64 + lane];
    float bias1[2] = {b1f[lx], b1f[16 + lx]};
    int laneoff = (lx << 1) + ((q >> 1) << 1) + (q & 1);                 // main-tile lane offset
    int colbT = 32 + ((lx & 1) << 1) + ((q >> 1) << 1) + (q & 1);        // tail-tile col part
    int rowT = lx >> 1;                                                  // tail-tile row part
    for (int m = wid; m < 39; m += 4) {
      f32x4 a1[2];
      a1[0] = (f32x4)0.f;
      a1[1] = (f32x4)0.f;
      int Gb;
      if (m < 34) Gb = m * 40 + laneoff;
      else        Gb = min((m - 34) * 8 + rowT, 33) * 40 + colbT;  // clamp: rows store-masked
#pragma unroll
      for (int s = 0; s < 6; ++s) {
        int G = Gb + (s >> 1) * 40 + (s & 1) * 4;
        int slot = G ^ ((G >> 3) & 7);
        short8 a = *(const short8*)&buf[slot * 8];
        a1[0] = __builtin_amdgcn_mfma_f32_16x16x32_bf16(a, bw1[s][0], a1[0], 0, 0, 0);
        a1[1] = __builtin_amdgcn_mfma_f32_16x16x32_bf16(a, bw1[s][1], a1[1], 0, 0, 0);
      }
      if (m < 34) {
        int base = (m * 18 + (q << 2)) * 18 + lx;
        if (!border) {
#pragma unroll
          for (int r = 0; r < 4; ++r) {
            float v0 = fmaxf(a1[0][r] + bias1[0], 0.f);
            float v1 = fmaxf(a1[1][r] + bias1[1], 0.f);
            x1u[base + r * 18] = pk2bf(v0, v1);
          }
        } else {
          bool gyok = (unsigned)(ty0 + m - 1) < 256u;
          int gx0 = tx0 - 1 + (q << 2);
#pragma unroll
          for (int r = 0; r < 4; ++r) {
            bool ok = gyok && ((unsigned)(gx0 + r) < 256u);
            float v0 = ok ? fmaxf(a1[0][r] + bias1[0], 0.f) : 0.f;
            float v1 = ok ? fmaxf(a1[1][r] + bias1[1], 0.f) : 0.f;
            x1u[base + r * 18] = pk2bf(v0, v1);
          }
        }
      } else {
        int tb = m - 34;
#pragma unroll
        for (int r = 0; r < 4; ++r) {
          int io = (q << 2) + r;
          int hy = tb * 8 + (io >> 1);
          int hx = 16 + (io & 1);
          if (hy < 34) {
            float v0 = fmaxf(a1[0][r] + bias1[0], 0.f);
            float v1 = fmaxf(a1[1][r] + bias1[1], 0.f);
            if (border) {
              bool ok = ((unsigned)(ty0 + hy - 1) < 256u) && ((unsigned)(tx0 + hx - 1) < 256u);
              v0 = ok ? v0 : 0.f;
              v1 = ok ? v1 : 0.f;
            }
            x1u[(hy * 18 + hx) * 18 + lx] = pk2bf(v0, v1);
          }
        }
      }
    }
  }
  __syncthreads();

  // ---- phase 3: conv2 + relayout + conv3 + aff store, in two 16-row halves ----
  float bias2q[4] = {b2f[lx], b2f[16 + lx], b2f[32 + lx], b2f[48 + lx]};
  short8 bw3[2];
  bw3[0] = w3fv[lane];
  bw3[1] = w3fv[64 + lane];
#pragma unroll
  for (int h = 0; h < 2; ++h) {
    f32x4 acc[4][4];
#pragma unroll
    for (int mt = 0; mt < 4; ++mt)
#pragma unroll
      for (int nt = 0; nt < 4; ++nt) acc[mt][nt] = (f32x4)0.f;
#pragma unroll
    for (int kk = 0; kk < 9; ++kk) {
      int ky = kk / 3, kx = kk - ky * 3;
      short8 a[4], b[4];
#pragma unroll
      for (int mt = 0; mt < 4; ++mt) {
        int row = h * 16 + wid * 4 + mt;
        a[mt] = *(const short8*)&x1t[((row + ky) * 18 + lx + kx) * 36 + q * 8];
      }
#pragma unroll
      for (int nt = 0; nt < 4; ++nt) b[nt] = w2fv[(kk * 4 + nt) * 64 + lane];
#pragma unroll
      for (int mt = 0; mt < 4; ++mt)
#pragma unroll
        for (int nt = 0; nt < 4; ++nt)
          acc[mt][nt] = __builtin_amdgcn_mfma_f32_16x16x32_bf16(a[mt], b[nt], acc[mt][nt], 0, 0, 0);
    }
    // h0: all waves must finish reading x1 rows 0..18 before the overlay clobbers rows 0..8.
    // h1: overlay writes (u<=17403) are disjoint from x1 rows>=16 (u>=21952) -> no barrier.
    if (h == 0) __syncthreads();
    // relayout this half's per-wave 64 px into overlay [p][68]
#pragma unroll
    for (int mt = 0; mt < 4; ++mt) {
      int prow = wid * 4 + mt;
#pragma unroll
      for (int r = 0; r < 4; ++r) {
        int p = prow * 16 + (q << 2) + r;
        uint2 pv;
        pv.x = pk2bf(fmaxf(acc[mt][0][r] + bias2q[0], 0.f),
                     fmaxf(acc[mt][1][r] + bias2q[1], 0.f));
        pv.y = pk2bf(fmaxf(acc[mt][2][r] + bias2q[2], 0.f),
                     fmaxf(acc[mt][3][r] + bias2q[3], 0.f));
        *(uint2*)&buf[p * 68 + (lx << 2)] = pv;
      }
    }
    // intra-wave cross-lane RAW through LDS (per-wave disjoint region)
    asm volatile("s_waitcnt lgkmcnt(0)" ::: "memory");
    __builtin_amdgcn_sched_barrier(0);
    f32x4 acc3[4];
#pragma unroll
    for (int mt = 0; mt < 4; ++mt) acc3[mt] = (f32x4)0.f;
#pragma unroll
    for (int mt = 0; mt < 4; ++mt) {
      int p = wid * 64 + mt * 16 + lx;
#pragma unroll
      for (int s = 0; s < 2; ++s) {
        short8 a3 = *(const short8*)&buf[p * 68 + s * 32 + q * 8];
        acc3[mt] = __builtin_amdgcn_mfma_f32_16x16x32_bf16(a3, bw3[s], acc3[mt], 0, 0, 0);
      }
    }
    // keep next half's overlay writes below this half's reads (cross-lane WAR)
    asm volatile("" ::: "memory");
    if (lx < 8) {
#pragma unroll
      for (int mt = 0; mt < 4; ++mt) {
        int py = ty0 + h * 16 + wid * 4 + mt;
        int px = tx0 + (q << 2);
        uint2 pv;
        pv.x = pk2bf(fmaxf(acc3[mt][0], 0.f), fmaxf(acc3[mt][1], 0.f));
        pv.y = pk2bf(fmaxf(acc3[mt][2], 0.f), fmaxf(acc3[mt][3], 0.f));
        *(uint2*)&aff[((size_t)(n * 8 + lx)) * HW + (size_t)py * WW + px] = pv;
      }
    }
  }
}

// ---------------- final: 8-neighbor softmax propagation, 4 px/thread ----------------
// XCD swizzle: 512 blocks = 8 x 64; one image's aff (1.05 MB) per XCD.
__global__ __launch_bounds__(256) void final_kernel(const float* __restrict__ disp,
                                                    const char* __restrict__ wsb,
                                                    float* __restrict__ out) {
  int bid = blockIdx.x;
  int sblk = ((bid & 7) << 6) + (bid >> 3);   // bijective (512 % 8 == 0)
  int gid = sblk * 256 + threadIdx.x;
  int n = gid >> 14;
  int r = gid & 16383;
  int i = r >> 6;
  int j0 = (r & 63) << 2;
  const ushort* aff = (const ushort*)(wsb + OFF_AFFB);
  float d6[3][6];
#pragma unroll
  for (int rr = 0; rr < 3; ++rr) {
    int y = min(max(i + rr - 1, 0), HH - 1);
    const float* dp = disp + (size_t)n * HW + y * WW;
    float4 c4 = *(const float4*)(dp + j0);
    d6[rr][1] = c4.x; d6[rr][2] = c4.y; d6[rr][3] = c4.z; d6[rr][4] = c4.w;
    d6[rr][0] = dp[max(j0 - 1, 0)];
    d6[rr][5] = dp[min(j0 + 4, WW - 1)];
  }
  const int dy[8] = {1, 1, 1, 0, 0, -1, -1, -1};
  const int dx[8] = {1, 0, -1, 1, -1, 1, 0, -1};
  float g[8][4], dvv[8][4];
#pragma unroll
  for (int k = 0; k < 8; ++k) {
    int y = i + dy[k];
    bool vy = (y >= 0 && y < HH);
    int yc = min(max(y, 0), HH - 1);
    const ushort* ap = aff + ((size_t)(n * 8 + k)) * HW + (size_t)yc * WW;
    float w6[6];
    u16x4 c4 = *(const u16x4*)(ap + j0);
    w6[1] = bf2f(c4[0]); w6[2] = bf2f(c4[1]); w6[3] = bf2f(c4[2]); w6[4] = bf2f(c4[3]);
    w6[0] = bf2f(ap[max(j0 - 1, 0)]);
    w6[5] = bf2f(ap[min(j0 + 4, WW - 1)]);
    int rr = dy[k] + 1;
#pragma unroll
    for (int p = 0; p < 4; ++p) {
      int xp = j0 + p + dx[k];
      bool ok = vy && (xp >= 0) && (xp < WW);
      g[k][p] = ok ? w6[p + 1 + dx[k]] : 0.f;
      dvv[k][p] = ok ? d6[rr][p + 1 + dx[k]] : 0.f;
    }
  }
  float4 res;
#pragma unroll
  for (int p = 0; p < 4; ++p) {
    float m = g[0][p];
#pragma unroll
    for (int k = 1; k < 8; ++k) m = fmaxf(m, g[k][p]);
    float se = 0.f, sed = 0.f;
#pragma unroll
    for (int k = 0; k < 8; ++k) {
      float e = __expf(g[k][p] - m);
      se += e;
      sed += e * dvv[k][p];
    }
    float dc = d6[1][p + 1];
    (&res.x)[p] = 0.3f * (sed / se) + 0.7f * dc;
  }
  *(float4*)(out + (size_t)n * HW + i * WW + j0) = res;
}

extern "C" void kernel_launch(void* const* d_in, const int* in_sizes, int n_in,
                              void* d_out, int out_size, void* d_ws, size_t ws_size,
                              hipStream_t stream) {
  const float* normal = (const float*)d_in[0];
  const float* left   = (const float*)d_in[1];
  const float* right  = (const float*)d_in[2];
  const float* disp   = (const float*)d_in[3];
  const float* w1 = (const float*)d_in[4];
  const float* g1 = (const float*)d_in[5];
  const float* b1 = (const float*)d_in[6];
  const float* m1 = (const float*)d_in[7];
  const float* v1 = (const float*)d_in[8];
  const float* w2 = (const float*)d_in[9];
  const float* g2 = (const float*)d_in[10];
  const float* b2 = (const float*)d_in[11];
  const float* m2 = (const float*)d_in[12];
  const float* v2 = (const float*)d_in[13];
  const float* w3 = (const float*)d_in[14];
  char* wsb  = (char*)d_ws;
  float* out = (float*)d_out;

  hipLaunchKernelGGL(feats_row, dim3(2149), dim3(256), 0, stream,
                     normal, left, right, disp,
                     w1, g1, b1, m1, v1, w2, g2, b2, m2, v2, w3, wsb);
  hipLaunchKernelGGL(trunk_kernel, dim3(1024), dim3(256), 0, stream, wsb);
  hipLaunchKernelGGL(final_kernel, dim3(512), dim3(256), 0, stream, disp, wsb, out);
}